// Round 3
// baseline (910.703 us; speedup 1.0000x reference)
//
#include <hip/hip_runtime.h>

#define NN 10000      // nodes
#define NE 160000     // edges
#define HF 512        // hidden/in features
#define LL 6          // layers
#define NC 64         // classes
#define KCAT (LL*HF)  // 3072
#define BN_EPS 1e-5f

typedef short bf16x8 __attribute__((ext_vector_type(8)));
typedef float f32x4 __attribute__((ext_vector_type(4)));

// round-to-nearest-even fp32 -> bf16 (bits), plus residual split
__device__ inline unsigned short bf16_rn(float z) {
  unsigned u = __float_as_uint(z);
  unsigned r = u + 0x7FFFu + ((u >> 16) & 1u);
  return (unsigned short)(r >> 16);
}
__device__ inline void split_bf16(float z, unsigned short& hi, unsigned short& lo) {
  unsigned u = __float_as_uint(z);
  unsigned rh = (u + 0x7FFFu + ((u >> 16) & 1u)) & 0xFFFF0000u;
  hi = (unsigned short)(rh >> 16);
  float fl = z - __uint_as_float(rh);
  lo = bf16_rn(fl);
}

// ---------------- setup kernels ----------------

__global__ void zero_u32_kernel(unsigned* __restrict__ p, int n) {
  int i = blockIdx.x * blockDim.x + threadIdx.x;
  if (i < n) p[i] = 0u;
}

__global__ void deg_kernel(const int* __restrict__ src, const int* __restrict__ dst,
                           unsigned* __restrict__ cnt_out, unsigned* __restrict__ cnt_in) {
  int e = blockIdx.x * blockDim.x + threadIdx.x;
  if (e < NE) {
    atomicAdd(&cnt_out[src[e]], 1u);
    atomicAdd(&cnt_in[dst[e]], 1u);
  }
}

__global__ void norm_kernel(const unsigned* __restrict__ cnt_out, const unsigned* __restrict__ cnt_in,
                            float* __restrict__ norm_src, float* __restrict__ norm_dst) {
  int i = blockIdx.x * blockDim.x + threadIdx.x;
  if (i < NN) {
    unsigned co = cnt_out[i]; if (co < 1u) co = 1u;
    unsigned ci = cnt_in[i];  if (ci < 1u) ci = 1u;
    norm_src[i] = rsqrtf((float)co);
    norm_dst[i] = rsqrtf((float)ci);
  }
}

// exclusive scan of cnt[0..NN) -> off[0..NN], single block of 1024
__global__ void scan_kernel(const unsigned* __restrict__ cnt, unsigned* __restrict__ off) {
  __shared__ unsigned wsum[16];
  int tid = threadIdx.x;
  int lane = tid & 63, wid = tid >> 6;
  unsigned base = 0;
  for (int c = 0; c < NN; c += 1024) {
    int i = c + tid;
    unsigned v = (i < NN) ? cnt[i] : 0u;
    unsigned x = v;
    #pragma unroll
    for (int d = 1; d < 64; d <<= 1) {
      unsigned y = __shfl_up(x, d, 64);
      if (lane >= d) x += y;
    }
    if (lane == 63) wsum[wid] = x;
    __syncthreads();
    if (wid == 0 && lane < 16) {
      unsigned s = wsum[lane];
      #pragma unroll
      for (int d = 1; d < 16; d <<= 1) {
        unsigned y = __shfl_up(s, d, 16);
        if (lane >= d) s += y;
      }
      wsum[lane] = s;
    }
    __syncthreads();
    unsigned wbase = wid ? wsum[wid - 1] : 0u;
    if (i < NN) off[i] = base + wbase + x - v;
    unsigned tot = wsum[15];
    __syncthreads();
    base += tot;
  }
  if (tid == 0) off[NN] = base;
}

__global__ void fill_kernel(const int* __restrict__ src, const int* __restrict__ dst,
                            const unsigned* __restrict__ off, unsigned* __restrict__ cursor,
                            int* __restrict__ edge_src) {
  int e = blockIdx.x * blockDim.x + threadIdx.x;
  if (e < NE) {
    int d = dst[e];
    unsigned p = atomicAdd(&cursor[d], 1u);
    edge_src[off[d] + p] = src[e];
  }
}

// ---------------- weight convert: W[k][n] fp32 -> Wt[n][k] bf16 hi/lo ----------------
// 32x32 LDS tile transpose; grid (16,16,6), 256 threads
__global__ void convert_w(const float* __restrict__ W0, const float* __restrict__ Ws,
                          unsigned short* __restrict__ Wthi, unsigned short* __restrict__ Wtlo) {
  int l = blockIdx.z;
  const float* W = (l == 0) ? W0 : (Ws + (size_t)(l - 1) * HF * HF);
  __shared__ float t[32][33];
  int n0 = blockIdx.x * 32, k0 = blockIdx.y * 32;
  int tx = threadIdx.x & 31, ty4 = (threadIdx.x >> 5) * 4;
  #pragma unroll
  for (int j = 0; j < 4; ++j)
    t[ty4 + j][tx] = W[(size_t)(k0 + ty4 + j) * HF + n0 + tx];
  __syncthreads();
  size_t base = (size_t)l * HF * HF;
  #pragma unroll
  for (int j = 0; j < 4; ++j) {
    unsigned short hi, lo;
    split_bf16(t[tx][ty4 + j], hi, lo);
    size_t idx = base + (size_t)(n0 + ty4 + j) * HF + k0 + tx;
    Wthi[idx] = hi;
    Wtlo[idx] = lo;
  }
}

// ---------------- split x*norm_src -> Zhi/Zlo ----------------
__global__ void split_x(const float* __restrict__ x, const float* __restrict__ nsrc,
                        unsigned short* __restrict__ zhi, unsigned short* __restrict__ zlo) {
  int i = blockIdx.x * blockDim.x + threadIdx.x;   // float4 index
  if (i >= NN * HF / 4) return;
  int base = i * 4;
  int row = base >> 9;
  float ns = nsrc[row];
  float4 v = *(const float4*)&x[base];
  ushort4 h4, l4;
  split_bf16(v.x * ns, h4.x, l4.x);
  split_bf16(v.y * ns, h4.y, l4.y);
  split_bf16(v.z * ns, h4.z, l4.z);
  split_bf16(v.w * ns, h4.w, l4.w);
  *(ushort4*)&zhi[base] = h4;
  *(ushort4*)&zlo[base] = l4;
}

// ---------------- layer GEMM via MFMA: m = Z @ W  (Z = hi+lo, W = hi+lo, 3 products) ----------------
// 128x128 tile, 4 waves, each wave 64x64 = 4x4 frags of 16x16x32_bf16. No LDS:
// A frag = 16B contiguous row slice of Z[NN][512]; B frag = 16B row slice of Wt[n][k].
__launch_bounds__(256)
__global__ void gemm_layer_mfma(const unsigned short* __restrict__ Zhi,
                                const unsigned short* __restrict__ Zlo,
                                const unsigned short* __restrict__ Wthi,
                                const unsigned short* __restrict__ Wtlo,
                                float* __restrict__ Mout) {
  int m0 = blockIdx.y * 128;
  int n0 = blockIdx.x * 128;
  int wid = threadIdx.x >> 6, lane = threadIdx.x & 63;
  int wr = wid >> 1, wc = wid & 1;
  int fr = lane & 15, kg = lane >> 4;

  f32x4 acc[4][4];
  #pragma unroll
  for (int m = 0; m < 4; ++m)
    #pragma unroll
    for (int n = 0; n < 4; ++n)
      acc[m][n] = (f32x4){0.f, 0.f, 0.f, 0.f};

  int arow[4]; bool aok[4];
  #pragma unroll
  for (int m = 0; m < 4; ++m) {
    arow[m] = m0 + wr * 64 + m * 16 + fr;
    aok[m] = arow[m] < NN;
  }
  int brow[4];
  #pragma unroll
  for (int n = 0; n < 4; ++n) brow[n] = n0 + wc * 64 + n * 16 + fr;

  const bf16x8 zv = (bf16x8){0,0,0,0,0,0,0,0};

  #pragma unroll 1
  for (int seg = 0; seg < 3; ++seg) {
    const unsigned short* Z  = (seg == 2) ? Zlo  : Zhi;
    const unsigned short* Wt = (seg == 1) ? Wtlo : Wthi;
    #pragma unroll 1
    for (int k0 = 0; k0 < HF; k0 += 32) {
      int koff = k0 + kg * 8;
      bf16x8 a[4], b[4];
      #pragma unroll
      for (int n = 0; n < 4; ++n)
        b[n] = *(const bf16x8*)&Wt[(size_t)brow[n] * HF + koff];
      #pragma unroll
      for (int m = 0; m < 4; ++m)
        a[m] = aok[m] ? *(const bf16x8*)&Z[(size_t)arow[m] * HF + koff] : zv;
      #pragma unroll
      for (int m = 0; m < 4; ++m)
        #pragma unroll
        for (int n = 0; n < 4; ++n)
          acc[m][n] = __builtin_amdgcn_mfma_f32_16x16x32_bf16(a[m], b[n], acc[m][n], 0, 0, 0);
    }
  }

  // C/D layout: col = lane&15, row = (lane>>4)*4 + j
  #pragma unroll
  for (int m = 0; m < 4; ++m) {
    #pragma unroll
    for (int j = 0; j < 4; ++j) {
      int row = m0 + wr * 64 + m * 16 + kg * 4 + j;
      if (row < NN) {
        #pragma unroll
        for (int n = 0; n < 4; ++n) {
          int col = n0 + wc * 64 + n * 16 + fr;
          Mout[(size_t)row * HF + col] = acc[m][n][j];
        }
      }
    }
  }
}

// ---------------- aggregation + norm_dst + bias + BN + ReLU (+ split for next layer) ----------------
__launch_bounds__(128)
__global__ void agg_bn_kernel(const float* __restrict__ Mm,
                              const int* __restrict__ edge_src,
                              const unsigned* __restrict__ row_off,
                              const float* __restrict__ norm_dst,
                              const float* __restrict__ norm_src,
                              const float* __restrict__ bias,
                              const float* __restrict__ gamma,
                              const float* __restrict__ beta,
                              const float* __restrict__ mean,
                              const float* __restrict__ var,
                              float* __restrict__ hcat_col,      // hcat + l*HF, row stride KCAT
                              unsigned short* __restrict__ zhi,  // may be null (last layer)
                              unsigned short* __restrict__ zlo) {
  int n = blockIdx.x;
  int f = threadIdx.x * 4;
  unsigned e0 = row_off[n], e1 = row_off[n + 1];
  float ax = 0.f, ay = 0.f, az = 0.f, aw = 0.f;
  unsigned e = e0;
  for (; e + 4 <= e1; e += 4) {
    int s0 = edge_src[e], s1 = edge_src[e + 1], s2 = edge_src[e + 2], s3 = edge_src[e + 3];
    float4 v0 = *(const float4*)&Mm[(size_t)s0 * HF + f];
    float4 v1 = *(const float4*)&Mm[(size_t)s1 * HF + f];
    float4 v2 = *(const float4*)&Mm[(size_t)s2 * HF + f];
    float4 v3 = *(const float4*)&Mm[(size_t)s3 * HF + f];
    ax += v0.x + v1.x + v2.x + v3.x;
    ay += v0.y + v1.y + v2.y + v3.y;
    az += v0.z + v1.z + v2.z + v3.z;
    aw += v0.w + v1.w + v2.w + v3.w;
  }
  for (; e < e1; ++e) {
    int s = edge_src[e];
    float4 v = *(const float4*)&Mm[(size_t)s * HF + f];
    ax += v.x; ay += v.y; az += v.z; aw += v.w;
  }
  float nd = norm_dst[n];
  float4 b  = *(const float4*)&bias[f];
  float4 g  = *(const float4*)&gamma[f];
  float4 bt = *(const float4*)&beta[f];
  float4 mu = *(const float4*)&mean[f];
  float4 vr = *(const float4*)&var[f];
  float sx = g.x * rsqrtf(vr.x + BN_EPS);
  float sy = g.y * rsqrtf(vr.y + BN_EPS);
  float sz = g.z * rsqrtf(vr.z + BN_EPS);
  float sw = g.w * rsqrtf(vr.w + BN_EPS);
  float yx = fmaxf((ax * nd + b.x - mu.x) * sx + bt.x, 0.f);
  float yy = fmaxf((ay * nd + b.y - mu.y) * sy + bt.y, 0.f);
  float yz = fmaxf((az * nd + b.z - mu.z) * sz + bt.z, 0.f);
  float yw = fmaxf((aw * nd + b.w - mu.w) * sw + bt.w, 0.f);
  *(float4*)&hcat_col[(size_t)n * KCAT + f] = make_float4(yx, yy, yz, yw);
  if (zhi) {
    float ns = norm_src[n];
    ushort4 h4, l4;
    split_bf16(yx * ns, h4.x, l4.x);
    split_bf16(yy * ns, h4.y, l4.y);
    split_bf16(yz * ns, h4.z, l4.z);
    split_bf16(yw * ns, h4.w, l4.w);
    *(ushort4*)&zhi[(size_t)n * HF + f] = h4;
    *(ushort4*)&zlo[(size_t)n * HF + f] = l4;
  }
}

// ---------------- final GEMM, split-K over 6 layer chunks (fp32) ----------------
__launch_bounds__(256)
__global__ void final_gemm_split(const float* __restrict__ hcat,
                                 const float* __restrict__ linW,   // [3072][64]
                                 float* __restrict__ part) {       // [6][NN][64]
  __shared__ float As[32][68];
  __shared__ float Bs[32][64];
  int tid = threadIdx.x;
  int m0 = blockIdx.x * 64;
  int sp = blockIdx.y;
  int kbase = sp * HF;
  int tx = tid & 15, ty = tid >> 4;
  float acc[4][4];
  #pragma unroll
  for (int i = 0; i < 4; ++i)
    #pragma unroll
    for (int j = 0; j < 4; ++j) acc[i][j] = 0.f;

  for (int kk = 0; kk < HF; kk += 32) {
    int k0 = kbase + kk;
    __syncthreads();
    #pragma unroll
    for (int p = 0; p < 2; ++p) {
      int idx = p * 256 + tid;
      int arow = idx >> 3;      // 0..63
      int akq  = idx & 7;       // 0..7
      int r = m0 + arow;
      float4 v = make_float4(0.f, 0.f, 0.f, 0.f);
      if (r < NN) v = *(const float4*)&hcat[(size_t)r * KCAT + k0 + akq * 4];
      As[akq * 4 + 0][arow] = v.x;
      As[akq * 4 + 1][arow] = v.y;
      As[akq * 4 + 2][arow] = v.z;
      As[akq * 4 + 3][arow] = v.w;
    }
    #pragma unroll
    for (int p = 0; p < 2; ++p) {
      int idx = p * 256 + tid;
      int bk = idx >> 4;        // 0..31
      int bq = idx & 15;        // 0..15
      *(float4*)&Bs[bk][bq * 4] = *(const float4*)&linW[(size_t)(k0 + bk) * NC + bq * 4];
    }
    __syncthreads();
    #pragma unroll
    for (int k = 0; k < 32; ++k) {
      float a[4], b[4];
      *(float4*)&a[0] = *(const float4*)&As[k][ty * 4];
      *(float4*)&b[0] = *(const float4*)&Bs[k][tx * 4];
      #pragma unroll
      for (int i = 0; i < 4; ++i)
        #pragma unroll
        for (int j = 0; j < 4; ++j)
          acc[i][j] = fmaf(a[i], b[j], acc[i][j]);
    }
  }
  #pragma unroll
  for (int i = 0; i < 4; ++i) {
    int r = m0 + ty * 4 + i;
    if (r < NN) {
      *(float4*)&part[((size_t)sp * NN + r) * NC + tx * 4] =
          make_float4(acc[i][0], acc[i][1], acc[i][2], acc[i][3]);
    }
  }
}

__launch_bounds__(256)
__global__ void final_reduce(const float* __restrict__ part,
                             const float* __restrict__ linb,
                             float* __restrict__ out) {
  int i = blockIdx.x * blockDim.x + threadIdx.x;   // float4 index
  if (i >= NN * NC / 4) return;
  int n  = i >> 4;
  int cq = i & 15;
  float4 s = *(const float4*)&linb[cq * 4];
  #pragma unroll
  for (int sp = 0; sp < LL; ++sp) {
    float4 v = *(const float4*)&part[((size_t)sp * NN + n) * NC + cq * 4];
    s.x += v.x; s.y += v.y; s.z += v.z; s.w += v.w;
  }
  *(float4*)&out[(size_t)n * NC + cq * 4] = s;
}

// ---------------- launch ----------------

extern "C" void kernel_launch(void* const* d_in, const int* in_sizes, int n_in,
                              void* d_out, int out_size, void* d_ws, size_t ws_size,
                              hipStream_t stream) {
  const float* x     = (const float*)d_in[0];
  const float* W0    = (const float*)d_in[1];
  const float* Ws    = (const float*)d_in[2];
  const float* bs    = (const float*)d_in[3];
  const float* gamma = (const float*)d_in[4];
  const float* beta  = (const float*)d_in[5];
  const float* rmean = (const float*)d_in[6];
  const float* rvar  = (const float*)d_in[7];
  const float* linW  = (const float*)d_in[8];
  const float* linb  = (const float*)d_in[9];
  const int*   src   = (const int*)d_in[10];
  const int*   dst   = (const int*)d_in[11];
  float* out = (float*)d_out;

  char* w = (char*)d_ws;
  size_t o = 0;
  auto carve = [&](size_t bytes) -> void* {
    o = (o + 255) & ~(size_t)255;
    void* p = w + o;
    o += bytes;
    return p;
  };
  float*          m_buf = (float*)carve((size_t)NN * HF * 4);
  float*          hcat  = (float*)carve((size_t)NN * KCAT * 4);
  float*          part  = (float*)carve((size_t)LL * NN * NC * 4);
  unsigned short* zhi   = (unsigned short*)carve((size_t)NN * HF * 2);
  unsigned short* zlo   = (unsigned short*)carve((size_t)NN * HF * 2);
  unsigned short* wthi  = (unsigned short*)carve((size_t)LL * HF * HF * 2);
  unsigned short* wtlo  = (unsigned short*)carve((size_t)LL * HF * HF * 2);
  float*          nsrc  = (float*)carve((size_t)NN * 4);
  float*          ndst  = (float*)carve((size_t)NN * 4);
  unsigned*       cnts  = (unsigned*)carve((size_t)3 * NN * 4);
  unsigned*       roff  = (unsigned*)carve((size_t)(NN + 1) * 4);
  int*            esrc  = (int*)carve((size_t)NE * 4);

  unsigned* cnt_out = cnts;
  unsigned* cnt_in  = cnts + NN;
  unsigned* cursor  = cnts + 2 * NN;

  zero_u32_kernel<<<(3 * NN + 255) / 256, 256, 0, stream>>>(cnts, 3 * NN);
  deg_kernel<<<(NE + 255) / 256, 256, 0, stream>>>(src, dst, cnt_out, cnt_in);
  norm_kernel<<<(NN + 255) / 256, 256, 0, stream>>>(cnt_out, cnt_in, nsrc, ndst);
  scan_kernel<<<1, 1024, 0, stream>>>(cnt_in, roff);
  fill_kernel<<<(NE + 255) / 256, 256, 0, stream>>>(src, dst, roff, cursor, esrc);
  convert_w<<<dim3(16, 16, 6), 256, 0, stream>>>(W0, Ws, wthi, wtlo);
  split_x<<<(NN * HF / 4 + 255) / 256, 256, 0, stream>>>(x, nsrc, zhi, zlo);

  for (int l = 0; l < LL; ++l) {
    gemm_layer_mfma<<<dim3(HF / 128, (NN + 127) / 128), 256, 0, stream>>>(
        zhi, zlo, wthi + (size_t)l * HF * HF, wtlo + (size_t)l * HF * HF, m_buf);
    bool last = (l == LL - 1);
    agg_bn_kernel<<<NN, 128, 0, stream>>>(m_buf, esrc, roff, ndst, nsrc,
                                          bs + l * HF, gamma + l * HF, beta + l * HF,
                                          rmean + l * HF, rvar + l * HF,
                                          hcat + (size_t)l * HF,
                                          last ? nullptr : zhi,
                                          last ? nullptr : zlo);
  }
  final_gemm_split<<<dim3((NN + 63) / 64, LL), 256, 0, stream>>>(hcat, linW, part);
  final_reduce<<<(NN * NC / 4 + 255) / 256, 256, 0, stream>>>(part, linb, out);
}

// Round 4
// 288.585 us; speedup vs baseline: 3.1557x; 3.1557x over previous
//
#include <hip/hip_runtime.h>

#define NN 10000      // nodes
#define NNPAD 10112   // padded to 79*128
#define NE 160000     // edges
#define HF 512        // hidden/in features
#define LL 6          // layers
#define NC 64         // classes
#define KCAT (LL*HF)  // 3072
#define BN_EPS 1e-5f

typedef _Float16 f16x8 __attribute__((ext_vector_type(8)));
typedef _Float16 f16x4 __attribute__((ext_vector_type(4)));
typedef float f32x4 __attribute__((ext_vector_type(4)));

#define GLB(p) ((const __attribute__((address_space(1))) void*)(p))
#define LDSP(p) ((__attribute__((address_space(3))) void*)(p))

// ---------------- setup kernels ----------------

__global__ void zero_u32_kernel(unsigned* __restrict__ p, int n) {
  int i = blockIdx.x * blockDim.x + threadIdx.x;
  if (i < n) p[i] = 0u;
}

__global__ void deg_kernel(const int* __restrict__ src, const int* __restrict__ dst,
                           unsigned* __restrict__ cnt_out, unsigned* __restrict__ cnt_in) {
  int e = blockIdx.x * blockDim.x + threadIdx.x;
  if (e < NE) {
    atomicAdd(&cnt_out[src[e]], 1u);
    atomicAdd(&cnt_in[dst[e]], 1u);
  }
}

__global__ void norm_kernel(const unsigned* __restrict__ cnt_out, const unsigned* __restrict__ cnt_in,
                            float* __restrict__ norm_src, float* __restrict__ norm_dst) {
  int i = blockIdx.x * blockDim.x + threadIdx.x;
  if (i < NN) {
    unsigned co = cnt_out[i]; if (co < 1u) co = 1u;
    unsigned ci = cnt_in[i];  if (ci < 1u) ci = 1u;
    norm_src[i] = rsqrtf((float)co);
    norm_dst[i] = rsqrtf((float)ci);
  }
}

// exclusive scan of cnt[0..NN) -> off[0..NN], single block of 1024
__global__ void scan_kernel(const unsigned* __restrict__ cnt, unsigned* __restrict__ off) {
  __shared__ unsigned wsum[16];
  int tid = threadIdx.x;
  int lane = tid & 63, wid = tid >> 6;
  unsigned base = 0;
  for (int c = 0; c < NN; c += 1024) {
    int i = c + tid;
    unsigned v = (i < NN) ? cnt[i] : 0u;
    unsigned x = v;
    #pragma unroll
    for (int d = 1; d < 64; d <<= 1) {
      unsigned y = __shfl_up(x, d, 64);
      if (lane >= d) x += y;
    }
    if (lane == 63) wsum[wid] = x;
    __syncthreads();
    if (wid == 0 && lane < 16) {
      unsigned s = wsum[lane];
      #pragma unroll
      for (int d = 1; d < 16; d <<= 1) {
        unsigned y = __shfl_up(s, d, 16);
        if (lane >= d) s += y;
      }
      wsum[lane] = s;
    }
    __syncthreads();
    unsigned wbase = wid ? wsum[wid - 1] : 0u;
    if (i < NN) off[i] = base + wbase + x - v;
    unsigned tot = wsum[15];
    __syncthreads();
    base += tot;
  }
  if (tid == 0) off[NN] = base;
}

__global__ void fill_kernel(const int* __restrict__ src, const int* __restrict__ dst,
                            const unsigned* __restrict__ off, unsigned* __restrict__ cursor,
                            int* __restrict__ edge_src) {
  int e = blockIdx.x * blockDim.x + threadIdx.x;
  if (e < NE) {
    int d = dst[e];
    unsigned p = atomicAdd(&cursor[d], 1u);
    edge_src[off[d] + p] = src[e];
  }
}

// ---------------- weight convert: W[k][n] fp32 -> Wt[n][k] fp16 ----------------
__global__ void convert_w(const float* __restrict__ W0, const float* __restrict__ Ws,
                          _Float16* __restrict__ Wt) {
  int l = blockIdx.z;
  const float* W = (l == 0) ? W0 : (Ws + (size_t)(l - 1) * HF * HF);
  __shared__ float t[32][33];
  int n0 = blockIdx.x * 32, k0 = blockIdx.y * 32;
  int tx = threadIdx.x & 31, ty4 = (threadIdx.x >> 5) * 4;
  #pragma unroll
  for (int j = 0; j < 4; ++j)
    t[ty4 + j][tx] = W[(size_t)(k0 + ty4 + j) * HF + n0 + tx];
  __syncthreads();
  size_t base = (size_t)l * HF * HF;
  #pragma unroll
  for (int j = 0; j < 4; ++j)
    Wt[base + (size_t)(n0 + ty4 + j) * HF + k0 + tx] = (_Float16)t[tx][ty4 + j];
}

// linW[k][c] fp32 -> Lt[c][k] fp16, k in [0,3072), c in [0,64)
__global__ void convert_lin(const float* __restrict__ linW, _Float16* __restrict__ Lt) {
  __shared__ float t[32][33];
  int n0 = blockIdx.x * 32, k0 = blockIdx.y * 32;
  int tx = threadIdx.x & 31, ty4 = (threadIdx.x >> 5) * 4;
  #pragma unroll
  for (int j = 0; j < 4; ++j)
    t[ty4 + j][tx] = linW[(size_t)(k0 + ty4 + j) * NC + n0 + tx];
  __syncthreads();
  #pragma unroll
  for (int j = 0; j < 4; ++j)
    Lt[(size_t)(n0 + ty4 + j) * KCAT + k0 + tx] = (_Float16)t[tx][ty4 + j];
}

// ---------------- x*norm_src -> zh fp16 ----------------
__global__ void split_x(const float* __restrict__ x, const float* __restrict__ nsrc,
                        _Float16* __restrict__ zh) {
  int i = blockIdx.x * blockDim.x + threadIdx.x;   // float4 index
  if (i >= NN * HF / 4) return;
  int base = i * 4;
  int row = base >> 9;
  float ns = nsrc[row];
  float4 v = *(const float4*)&x[base];
  f16x4 h;
  h.x = (_Float16)(v.x * ns);
  h.y = (_Float16)(v.y * ns);
  h.z = (_Float16)(v.z * ns);
  h.w = (_Float16)(v.w * ns);
  *(f16x4*)&zh[base] = h;
}

// ---------------- layer GEMM via MFMA, LDS-staged (m97 structure) ----------------
// Z[NNPAD][512] fp16 row-major; Wt[512][512] fp16 (pre-transposed, row = output col).
// 128x128 tile, BK=64, 4 waves (2x2), wave tile 64x64 = 4x4 frags of 16x16x32_f16.
// global_load_lds w=16 with pre-swizzled source chunk (c ^= row&7); swizzled ds_read.
__launch_bounds__(256, 2)
__global__ void gemm_layer_f16(const _Float16* __restrict__ Z,
                               const _Float16* __restrict__ Wt,
                               _Float16* __restrict__ Mout) {
  __shared__ _Float16 As[128][64];
  __shared__ _Float16 Bs[128][64];
  int m0 = blockIdx.y * 128;
  int n0 = blockIdx.x * 128;
  int wid = threadIdx.x >> 6, lane = threadIdx.x & 63;
  int wr = wid >> 1, wc = wid & 1;
  int fr = lane & 15, kg = lane >> 4;
  int rr = lane >> 3;            // staging row within 8-row group
  int ck = (lane & 7) ^ rr;      // pre-swizzled source chunk

  f32x4 acc[4][4];
  #pragma unroll
  for (int m = 0; m < 4; ++m)
    #pragma unroll
    for (int n = 0; n < 4; ++n)
      acc[m][n] = (f32x4){0.f, 0.f, 0.f, 0.f};

  const _Float16* gA = Z  + (size_t)(m0 + wid * 32 + rr) * HF + ck * 8;
  const _Float16* gB = Wt + (size_t)(n0 + wid * 32 + rr) * HF + ck * 8;

  for (int k0 = 0; k0 < HF; k0 += 64) {
    __syncthreads();
    #pragma unroll
    for (int i = 0; i < 4; ++i) {
      __builtin_amdgcn_global_load_lds(GLB(gA + (size_t)i * 8 * HF + k0),
                                       LDSP(&As[wid * 32 + i * 8][0]), 16, 0, 0);
      __builtin_amdgcn_global_load_lds(GLB(gB + (size_t)i * 8 * HF + k0),
                                       LDSP(&Bs[wid * 32 + i * 8][0]), 16, 0, 0);
    }
    __syncthreads();
    #pragma unroll
    for (int kk = 0; kk < 2; ++kk) {
      f16x8 a[4], b[4];
      #pragma unroll
      for (int n = 0; n < 4; ++n) {
        int row = wc * 64 + n * 16 + fr;
        b[n] = *(const f16x8*)&Bs[row][((kk * 4 + kg) ^ (row & 7)) * 8];
      }
      #pragma unroll
      for (int m = 0; m < 4; ++m) {
        int row = wr * 64 + m * 16 + fr;
        a[m] = *(const f16x8*)&As[row][((kk * 4 + kg) ^ (row & 7)) * 8];
      }
      #pragma unroll
      for (int m = 0; m < 4; ++m)
        #pragma unroll
        for (int n = 0; n < 4; ++n)
          acc[m][n] = __builtin_amdgcn_mfma_f32_16x16x32_f16(a[m], b[n], acc[m][n], 0, 0, 0);
    }
  }
  // C/D layout: col = lane&15, row = (lane>>4)*4 + j
  #pragma unroll
  for (int m = 0; m < 4; ++m) {
    #pragma unroll
    for (int j = 0; j < 4; ++j) {
      int row = m0 + wr * 64 + m * 16 + kg * 4 + j;
      if (row < NN) {
        #pragma unroll
        for (int n = 0; n < 4; ++n) {
          int col = n0 + wc * 64 + n * 16 + fr;
          Mout[(size_t)row * HF + col] = (_Float16)acc[m][n][j];
        }
      }
    }
  }
}

// ---------------- aggregation + norm_dst + bias + BN + ReLU (fp16 in/out) ----------------
__launch_bounds__(128)
__global__ void agg_bn_kernel(const _Float16* __restrict__ Mm,
                              const int* __restrict__ edge_src,
                              const unsigned* __restrict__ row_off,
                              const float* __restrict__ norm_dst,
                              const float* __restrict__ norm_src,
                              const float* __restrict__ bias,
                              const float* __restrict__ gamma,
                              const float* __restrict__ beta,
                              const float* __restrict__ mean,
                              const float* __restrict__ var,
                              _Float16* __restrict__ hcat_col,   // hcat + l*HF, row stride KCAT
                              _Float16* __restrict__ zh) {       // may be null (last layer)
  int n = blockIdx.x;
  int f = threadIdx.x * 4;
  unsigned e0 = row_off[n], e1 = row_off[n + 1];
  float ax = 0.f, ay = 0.f, az = 0.f, aw = 0.f;
  unsigned e = e0;
  for (; e + 4 <= e1; e += 4) {
    int s0 = edge_src[e], s1 = edge_src[e + 1], s2 = edge_src[e + 2], s3 = edge_src[e + 3];
    f16x4 v0 = *(const f16x4*)&Mm[(size_t)s0 * HF + f];
    f16x4 v1 = *(const f16x4*)&Mm[(size_t)s1 * HF + f];
    f16x4 v2 = *(const f16x4*)&Mm[(size_t)s2 * HF + f];
    f16x4 v3 = *(const f16x4*)&Mm[(size_t)s3 * HF + f];
    ax += (float)v0.x + (float)v1.x + (float)v2.x + (float)v3.x;
    ay += (float)v0.y + (float)v1.y + (float)v2.y + (float)v3.y;
    az += (float)v0.z + (float)v1.z + (float)v2.z + (float)v3.z;
    aw += (float)v0.w + (float)v1.w + (float)v2.w + (float)v3.w;
  }
  for (; e < e1; ++e) {
    int s = edge_src[e];
    f16x4 v = *(const f16x4*)&Mm[(size_t)s * HF + f];
    ax += (float)v.x; ay += (float)v.y; az += (float)v.z; aw += (float)v.w;
  }
  float nd = norm_dst[n];
  float4 b  = *(const float4*)&bias[f];
  float4 g  = *(const float4*)&gamma[f];
  float4 bt = *(const float4*)&beta[f];
  float4 mu = *(const float4*)&mean[f];
  float4 vr = *(const float4*)&var[f];
  float sx = g.x * rsqrtf(vr.x + BN_EPS);
  float sy = g.y * rsqrtf(vr.y + BN_EPS);
  float sz = g.z * rsqrtf(vr.z + BN_EPS);
  float sw = g.w * rsqrtf(vr.w + BN_EPS);
  float yx = fmaxf((ax * nd + b.x - mu.x) * sx + bt.x, 0.f);
  float yy = fmaxf((ay * nd + b.y - mu.y) * sy + bt.y, 0.f);
  float yz = fmaxf((az * nd + b.z - mu.z) * sz + bt.z, 0.f);
  float yw = fmaxf((aw * nd + b.w - mu.w) * sw + bt.w, 0.f);
  f16x4 hv;
  hv.x = (_Float16)yx; hv.y = (_Float16)yy; hv.z = (_Float16)yz; hv.w = (_Float16)yw;
  *(f16x4*)&hcat_col[(size_t)n * KCAT + f] = hv;
  if (zh) {
    float ns = norm_src[n];
    f16x4 zv;
    zv.x = (_Float16)(yx * ns); zv.y = (_Float16)(yy * ns);
    zv.z = (_Float16)(yz * ns); zv.w = (_Float16)(yw * ns);
    *(f16x4*)&zh[(size_t)n * HF + f] = zv;
  }
}

// ---------------- final GEMM via MFMA, split-K over 6 chunks ----------------
// Hc[NNPAD][3072] fp16, Lt[64][3072] fp16. BM=128, BN=64, BK=64; 4 waves, each 32 rows,
// frags 2m x 4n of 16x16x32_f16. grid (79, 6) -> part[6][NN][64] fp32.
__launch_bounds__(256, 2)
__global__ void final_gemm_f16(const _Float16* __restrict__ Hc,
                               const _Float16* __restrict__ Lt,
                               float* __restrict__ part) {
  __shared__ _Float16 As[128][64];
  __shared__ _Float16 Bs[64][64];
  int m0 = blockIdx.x * 128;
  int sp = blockIdx.y;
  int kbase = sp * HF;
  int wid = threadIdx.x >> 6, lane = threadIdx.x & 63;
  int fr = lane & 15, kg = lane >> 4;
  int rr = lane >> 3;
  int ck = (lane & 7) ^ rr;

  f32x4 acc[2][4];
  #pragma unroll
  for (int m = 0; m < 2; ++m)
    #pragma unroll
    for (int n = 0; n < 4; ++n)
      acc[m][n] = (f32x4){0.f, 0.f, 0.f, 0.f};

  const _Float16* gA = Hc + (size_t)(m0 + wid * 32 + rr) * KCAT + kbase + ck * 8;
  const _Float16* gB = Lt + (size_t)(wid * 16 + rr) * KCAT + kbase + ck * 8;

  for (int k0 = 0; k0 < HF; k0 += 64) {
    __syncthreads();
    #pragma unroll
    for (int i = 0; i < 4; ++i)
      __builtin_amdgcn_global_load_lds(GLB(gA + (size_t)i * 8 * KCAT + k0),
                                       LDSP(&As[wid * 32 + i * 8][0]), 16, 0, 0);
    #pragma unroll
    for (int i = 0; i < 2; ++i)
      __builtin_amdgcn_global_load_lds(GLB(gB + (size_t)i * 8 * KCAT + k0),
                                       LDSP(&Bs[wid * 16 + i * 8][0]), 16, 0, 0);
    __syncthreads();
    #pragma unroll
    for (int kk = 0; kk < 2; ++kk) {
      f16x8 a[2], b[4];
      #pragma unroll
      for (int n = 0; n < 4; ++n) {
        int row = n * 16 + fr;
        b[n] = *(const f16x8*)&Bs[row][((kk * 4 + kg) ^ (row & 7)) * 8];
      }
      #pragma unroll
      for (int m = 0; m < 2; ++m) {
        int row = wid * 32 + m * 16 + fr;
        a[m] = *(const f16x8*)&As[row][((kk * 4 + kg) ^ (row & 7)) * 8];
      }
      #pragma unroll
      for (int m = 0; m < 2; ++m)
        #pragma unroll
        for (int n = 0; n < 4; ++n)
          acc[m][n] = __builtin_amdgcn_mfma_f32_16x16x32_f16(a[m], b[n], acc[m][n], 0, 0, 0);
    }
  }
  #pragma unroll
  for (int m = 0; m < 2; ++m) {
    #pragma unroll
    for (int j = 0; j < 4; ++j) {
      int row = m0 + wid * 32 + m * 16 + kg * 4 + j;
      if (row < NN) {
        #pragma unroll
        for (int n = 0; n < 4; ++n) {
          int col = n * 16 + fr;
          part[((size_t)sp * NN + row) * NC + col] = acc[m][n][j];
        }
      }
    }
  }
}

__launch_bounds__(256)
__global__ void final_reduce(const float* __restrict__ part,
                             const float* __restrict__ linb,
                             float* __restrict__ out) {
  int i = blockIdx.x * blockDim.x + threadIdx.x;   // float4 index
  if (i >= NN * NC / 4) return;
  int n  = i >> 4;
  int cq = i & 15;
  float4 s = *(const float4*)&linb[cq * 4];
  #pragma unroll
  for (int sp = 0; sp < LL; ++sp) {
    float4 v = *(const float4*)&part[((size_t)sp * NN + n) * NC + cq * 4];
    s.x += v.x; s.y += v.y; s.z += v.z; s.w += v.w;
  }
  *(float4*)&out[(size_t)n * NC + cq * 4] = s;
}

// ---------------- launch ----------------

extern "C" void kernel_launch(void* const* d_in, const int* in_sizes, int n_in,
                              void* d_out, int out_size, void* d_ws, size_t ws_size,
                              hipStream_t stream) {
  const float* x     = (const float*)d_in[0];
  const float* W0    = (const float*)d_in[1];
  const float* Ws    = (const float*)d_in[2];
  const float* bs    = (const float*)d_in[3];
  const float* gamma = (const float*)d_in[4];
  const float* beta  = (const float*)d_in[5];
  const float* rmean = (const float*)d_in[6];
  const float* rvar  = (const float*)d_in[7];
  const float* linW  = (const float*)d_in[8];
  const float* linb  = (const float*)d_in[9];
  const int*   src   = (const int*)d_in[10];
  const int*   dst   = (const int*)d_in[11];
  float* out = (float*)d_out;

  char* w = (char*)d_ws;
  size_t o = 0;
  auto carve = [&](size_t bytes) -> void* {
    o = (o + 255) & ~(size_t)255;
    void* p = w + o;
    o += bytes;
    return p;
  };
  _Float16*  m_buf = (_Float16*)carve((size_t)NNPAD * HF * 2);
  _Float16*  hcat  = (_Float16*)carve((size_t)NNPAD * KCAT * 2);
  _Float16*  zh    = (_Float16*)carve((size_t)NNPAD * HF * 2);
  _Float16*  wt    = (_Float16*)carve((size_t)LL * HF * HF * 2);
  _Float16*  lt    = (_Float16*)carve((size_t)NC * KCAT * 2);
  float*     part  = (float*)carve((size_t)LL * NN * NC * 4);
  float*     nsrc  = (float*)carve((size_t)NN * 4);
  float*     ndst  = (float*)carve((size_t)NN * 4);
  unsigned*  cnts  = (unsigned*)carve((size_t)3 * NN * 4);
  unsigned*  roff  = (unsigned*)carve((size_t)(NN + 1) * 4);
  int*       esrc  = (int*)carve((size_t)NE * 4);

  unsigned* cnt_out = cnts;
  unsigned* cnt_in  = cnts + NN;
  unsigned* cursor  = cnts + 2 * NN;

  zero_u32_kernel<<<(3 * NN + 255) / 256, 256, 0, stream>>>(cnts, 3 * NN);
  deg_kernel<<<(NE + 255) / 256, 256, 0, stream>>>(src, dst, cnt_out, cnt_in);
  norm_kernel<<<(NN + 255) / 256, 256, 0, stream>>>(cnt_out, cnt_in, nsrc, ndst);
  scan_kernel<<<1, 1024, 0, stream>>>(cnt_in, roff);
  fill_kernel<<<(NE + 255) / 256, 256, 0, stream>>>(src, dst, roff, cursor, esrc);
  convert_w<<<dim3(16, 16, 6), 256, 0, stream>>>(W0, Ws, wt);
  convert_lin<<<dim3(2, 96), 256, 0, stream>>>(linW, lt);
  split_x<<<(NN * HF / 4 + 255) / 256, 256, 0, stream>>>(x, nsrc, zh);

  for (int l = 0; l < LL; ++l) {
    gemm_layer_f16<<<dim3(HF / 128, NNPAD / 128), 256, 0, stream>>>(
        zh, wt + (size_t)l * HF * HF, m_buf);
    bool last = (l == LL - 1);
    agg_bn_kernel<<<NN, 128, 0, stream>>>(m_buf, esrc, roff, ndst, nsrc,
                                          bs + l * HF, gamma + l * HF, beta + l * HF,
                                          rmean + l * HF, rvar + l * HF,
                                          hcat + (size_t)l * HF,
                                          last ? nullptr : zh);
  }
  final_gemm_f16<<<dim3(NNPAD / 128, LL), 256, 0, stream>>>(hcat, lt, part);
  final_reduce<<<(NN * NC / 4 + 255) / 256, 256, 0, stream>>>(part, linb, out);
}